// Round 15
// baseline (398.337 us; speedup 1.0000x reference)
//
#include <hip/hip_runtime.h>

#define NN 100000
#define BSHIFT 8
#define NB 391        // ceil(NN / 256)
#define EPA 4096      // edges per stage block
#define SCAP_SHIFT 12 // 4096 ints per fixed bucket region (mean 2046, +45 sigma safe)

typedef unsigned short ushort_t;
typedef float v2f __attribute__((ext_vector_type(2)));

__device__ inline ushort_t f2bf(float f) {
    unsigned int b = __float_as_uint(f);
    unsigned int r = (b + 0x7FFFu + ((b >> 16) & 1u)) >> 16;
    return (ushort_t)r;
}
// pack 2 floats -> 1 u32 of 2 bf16
__device__ inline int pk2(float a, float b) {
    return (int)((unsigned int)f2bf(a) | ((unsigned int)f2bf(b) << 16));
}
// unpack 2 bf16 (packed in int) -> float2; add compiles to v_pk_add_f32
__device__ inline v2f unpk(int u) {
    v2f r;
    r.x = __int_as_float(u << 16);
    r.y = __int_as_float(u & 0xffff0000);
    return r;
}

// ---------------- zero bucket fill counters ----------------
__global__ __launch_bounds__(256) void zero_small(int* __restrict__ p, int n) {
    int i = blockIdx.x * 256 + threadIdx.x;
    if (i < n) p[i] = 0;
}

// ---------------- single-pass stage into fixed-capacity bucket regions ----------------
__global__ __launch_bounds__(256) void stage_edges(const int* __restrict__ src,
                                                   const int* __restrict__ dst,
                                                   int* __restrict__ gfill,
                                                   int* __restrict__ stage, int E) {
    __shared__ int hist[NB];
    __shared__ int base[NB];
    const int tid = threadIdx.x;
    const int e0 = blockIdx.x * EPA;
    for (int i = tid; i < NB; i += 256) hist[i] = 0;
    __syncthreads();
    int es[16], eb[16];
#pragma unroll
    for (int k = 0; k < 16; ++k) {
        int e = e0 + k * 256 + tid;
        if (e < E) {
            int d = dst[e];
            eb[k] = d >> BSHIFT;
            es[k] = src[e] | ((d & 255) << 17);
            atomicAdd(&hist[eb[k]], 1);
        } else {
            eb[k] = -1;
        }
    }
    __syncthreads();
    for (int i = tid; i < NB; i += 256) {
        int c = hist[i];
        int g = (c > 0) ? atomicAdd(&gfill[i], c) : 0;
        base[i] = (i << SCAP_SHIFT) + g;
        hist[i] = 0;   // reuse as running offset
    }
    __syncthreads();
#pragma unroll
    for (int k = 0; k < 16; ++k) {
        if (eb[k] >= 0) {
            int idx = atomicAdd(&hist[eb[k]], 1);
            stage[base[eb[k]] + idx] = es[k];
        }
    }
}

// ---------------- scan 391 bucket fills -> bbase (exclusive); row_ptr[N] = E ----------------
__global__ __launch_bounds__(512) void scan_buckets(const int* __restrict__ gfill,
                                                    int* __restrict__ bbase,
                                                    int* __restrict__ row_ptr, int N) {
    __shared__ int s[512];
    const int tid = threadIdx.x;
    int v = (tid < NB) ? gfill[tid] : 0;
    s[tid] = v;
    __syncthreads();
    for (int off = 1; off < 512; off <<= 1) {
        int t = (tid >= off) ? s[tid - off] : 0;
        __syncthreads();
        if (tid >= off) s[tid] += t;
        __syncthreads();
    }
    if (tid < NB) bbase[tid] = s[tid] - v;       // exclusive
    if (tid == NB - 1) {
        bbase[NB] = s[tid];
        row_ptr[N] = s[tid];                      // = E
    }
}

// ---------------- per-bucket build: counts -> row_ptr + dinv_sqrt + place col ----------------
__global__ __launch_bounds__(256) void build_csr(const int* __restrict__ bbase,
                                                 const int* __restrict__ stage,
                                                 int* __restrict__ row_ptr,
                                                 float* __restrict__ dinv_sqrt,
                                                 int* __restrict__ col, int N) {
    __shared__ int cnt[256];
    __shared__ int rp[257];
    __shared__ int lfill[256];
    __shared__ int wsum[4];
    const int tid = threadIdx.x, lane = tid & 63, wid = tid >> 6;
    const int lo = blockIdx.x << BSHIFT;
    const int nn = min(256, N - lo);
    const int e0 = bbase[blockIdx.x];
    const int cntE = bbase[blockIdx.x + 1] - e0;
    const int* st = stage + ((size_t)blockIdx.x << SCAP_SHIFT);
    cnt[tid] = 0;
    lfill[tid] = 0;
    __syncthreads();
    for (int e = tid; e < cntE; e += 256)
        atomicAdd(&cnt[(st[e] >> 17) & 255], 1);
    __syncthreads();
    int v = cnt[tid];
    int x = v;
#pragma unroll
    for (int off = 1; off < 64; off <<= 1) {
        int y = __shfl_up(x, off, 64);
        if (lane >= off) x += y;
    }
    if (lane == 63) wsum[wid] = x;
    __syncthreads();
    int woff = 0;
    for (int w = 0; w < wid; ++w) woff += wsum[w];
    rp[tid] = e0 + woff + (x - v);
    if (tid == 255) rp[256] = e0 + woff + x;
    if (tid < nn) {
        row_ptr[lo + tid] = e0 + woff + (x - v);
        dinv_sqrt[lo + tid] = rsqrtf((float)v + 1.0f);
    }
    __syncthreads();
    for (int e = tid; e < cntE; e += 256) {
        int s = st[e];
        int dloc = (s >> 17) & 255;
        int pos = rp[dloc] + atomicAdd(&lfill[dloc], 1);
        col[pos] = s & 0x1FFFF;
    }
}

// ---------------- edge sum: 8 features/lane (int4 = 8 bf16, 16B gather), pk-f32 adds ----------------
template <int F>
__device__ inline void agg_edges_v8(const ushort_t* __restrict__ h,
                                    const int* __restrict__ col,
                                    int e0, int e1, int fb, v2f* __restrict__ acc) {
    int e = e0;
    for (; e + 8 <= e1; e += 8) {
        int c[8];
#pragma unroll
        for (int j = 0; j < 8; ++j) c[j] = col[e + j];
        int4 q[8];
#pragma unroll
        for (int j = 0; j < 8; ++j) q[j] = *(const int4*)(h + (size_t)c[j] * F + fb);
#pragma unroll
        for (int j = 0; j < 8; ++j) {
            acc[0] += unpk(q[j].x);
            acc[1] += unpk(q[j].y);
            acc[2] += unpk(q[j].z);
            acc[3] += unpk(q[j].w);
        }
    }
    if (e + 4 <= e1) {
        int c[4];
#pragma unroll
        for (int j = 0; j < 4; ++j) c[j] = col[e + j];
        int4 q[4];
#pragma unroll
        for (int j = 0; j < 4; ++j) q[j] = *(const int4*)(h + (size_t)c[j] * F + fb);
#pragma unroll
        for (int j = 0; j < 4; ++j) {
            acc[0] += unpk(q[j].x);
            acc[1] += unpk(q[j].y);
            acc[2] += unpk(q[j].z);
            acc[3] += unpk(q[j].w);
        }
        e += 4;
    }
    for (; e < e1; ++e) {
        int4 q = *(const int4*)(h + (size_t)col[e] * F + fb);
        acc[0] += unpk(q.x);
        acc[1] += unpk(q.y);
        acc[2] += unpk(q.z);
        acc[3] += unpk(q.w);
    }
}

// ---------------- dense GEMM h' = ds[row] * (in @ W), W staged as bf16, bf16 out ----------------
template <int FOUT, int R>
__global__ __launch_bounds__(256) void gemm_lds(const float* __restrict__ in,
                                                const float* __restrict__ W,
                                                const float* __restrict__ ds, int n,
                                                ushort_t* __restrict__ h) {
    constexpr int XS = 68;
    __shared__ float xs[R * XS];
    __shared__ int wsb[64 * FOUT / 2];   // packed bf16 pairs (col-major pairs)
    const int tid = threadIdx.x;
    const int r0 = blockIdx.x * R;
    {
        const float4* xsrc = (const float4*)(in + (size_t)r0 * 64);
        constexpr int NF4 = R * 16;
#pragma unroll
        for (int i = tid; i < NF4; i += 256) {
            int row = i >> 4, kk = (i & 15) << 2;
            float4 v = make_float4(0.f, 0.f, 0.f, 0.f);
            if (r0 + row < n) v = xsrc[i];
            *(float4*)(xs + row * XS + kk) = v;
        }
        const float4* wsrc = (const float4*)W;
#pragma unroll
        for (int i = tid; i < 64 * FOUT / 4; i += 256) {
            float4 v = wsrc[i];
            int2 p;
            p.x = pk2(v.x, v.y);
            p.y = pk2(v.z, v.w);
            *(int2*)(wsb + i * 2) = p;
        }
    }
    __syncthreads();
    constexpr int CG = FOUT / 4;
    const int row = tid / CG;
    const int col = (tid % CG) * 4;
    float4 acc = make_float4(0.f, 0.f, 0.f, 0.f);
#pragma unroll
    for (int k = 0; k < 64; k += 4) {
        float4 xv = *(const float4*)(xs + row * XS + k);
#pragma unroll
        for (int kk = 0; kk < 4; ++kk) {
            float a = (&xv.x)[kk];
            int2 wp = *(const int2*)(wsb + ((k + kk) * FOUT + col) / 2);
            v2f w0 = unpk(wp.x), w1 = unpk(wp.y);
            acc.x = fmaf(a, w0.x, acc.x);
            acc.y = fmaf(a, w0.y, acc.y);
            acc.z = fmaf(a, w1.x, acc.z);
            acc.w = fmaf(a, w1.y, acc.w);
        }
    }
    int orow = r0 + row;
    if (orow < n) {
        float dsv = ds[orow];
        ushort4 o;
        o.x = f2bf(acc.x * dsv); o.y = f2bf(acc.y * dsv);
        o.z = f2bf(acc.z * dsv); o.w = f2bf(acc.w * dsv);
        *(ushort4*)(h + (size_t)orow * FOUT + col) = o;
    }
}

// ---------------- FUSED agg+gemm: 8 lanes/row (16B gathers), 8 rows/wave, R=32 ----------------
// W staged as packed bf16 -> ~17KB LDS -> 8 blocks/CU (full 32-wave occupancy).
template <int FOUT>
__global__ __launch_bounds__(256) void agg_gemm(const ushort_t* __restrict__ hin,
                                                const int* __restrict__ row_ptr,
                                                const int* __restrict__ col,
                                                const float* __restrict__ ds,
                                                const float* __restrict__ bagg,
                                                const float* __restrict__ W, int n,
                                                ushort_t* __restrict__ hout) {
    constexpr int R = 32;
    constexpr int XS = 68;
    __shared__ float xs[R * XS];
    __shared__ int wsb[64 * FOUT / 2];
    __shared__ int rp[R + 1];
    const int tid = threadIdx.x, lane = tid & 63, wid = tid >> 6;
    const int r0 = blockIdx.x * R;
    // stage W (packed bf16)
    const float4* wsrc = (const float4*)W;
#pragma unroll
    for (int i = tid; i < 64 * FOUT / 4; i += 256) {
        float4 v = wsrc[i];
        int2 p;
        p.x = pk2(v.x, v.y);
        p.y = pk2(v.z, v.w);
        *(int2*)(wsb + i * 2) = p;
    }
    if (tid <= R) rp[tid] = row_ptr[min(r0 + tid, n)];
    __syncthreads();
    // phase A: 8 rows per wave, 8 lanes per row, 8 features/lane
    {
        const int sub = lane >> 3;        // 0..7
        const int fb = (lane & 7) * 8;    // feature offset
        const int row = wid * 8 + sub;
        const int g = r0 + row;
        v2f acc[4];
        acc[0] = 0.f; acc[1] = 0.f; acc[2] = 0.f; acc[3] = 0.f;
        if (g < n) {
            int4 q = *(const int4*)(hin + (size_t)g * 64 + fb);
            acc[0] = unpk(q.x); acc[1] = unpk(q.y);
            acc[2] = unpk(q.z); acc[3] = unpk(q.w);
            agg_edges_v8<64>(hin, col, rp[row], rp[row + 1], fb, acc);
            float dsv = ds[g];
            float4 b0 = *(const float4*)(bagg + fb);
            float4 b1 = *(const float4*)(bagg + fb + 4);
            acc[0].x = fmaxf(fmaf(acc[0].x, dsv, b0.x), 0.f);
            acc[0].y = fmaxf(fmaf(acc[0].y, dsv, b0.y), 0.f);
            acc[1].x = fmaxf(fmaf(acc[1].x, dsv, b0.z), 0.f);
            acc[1].y = fmaxf(fmaf(acc[1].y, dsv, b0.w), 0.f);
            acc[2].x = fmaxf(fmaf(acc[2].x, dsv, b1.x), 0.f);
            acc[2].y = fmaxf(fmaf(acc[2].y, dsv, b1.y), 0.f);
            acc[3].x = fmaxf(fmaf(acc[3].x, dsv, b1.z), 0.f);
            acc[3].y = fmaxf(fmaf(acc[3].y, dsv, b1.w), 0.f);
        }
        float4 o0 = make_float4(acc[0].x, acc[0].y, acc[1].x, acc[1].y);
        float4 o1 = make_float4(acc[2].x, acc[2].y, acc[3].x, acc[3].y);
        *(float4*)(xs + row * XS + fb) = o0;
        *(float4*)(xs + row * XS + fb + 4) = o1;
    }
    __syncthreads();
    // phase B: GEMM from xs, hout = ds * (xs @ W), bf16
    constexpr int CG = FOUT / 4;
    for (int o = tid; o < R * CG; o += 256) {
        int row = o / CG;
        int cg = (o % CG) * 4;
        float4 acc = make_float4(0.f, 0.f, 0.f, 0.f);
#pragma unroll
        for (int k = 0; k < 64; k += 4) {
            float4 xv = *(const float4*)(xs + row * XS + k);
#pragma unroll
            for (int kk = 0; kk < 4; ++kk) {
                float a = (&xv.x)[kk];
                int2 wp = *(const int2*)(wsb + ((k + kk) * FOUT + cg) / 2);
                v2f w0 = unpk(wp.x), w1 = unpk(wp.y);
                acc.x = fmaf(a, w0.x, acc.x);
                acc.y = fmaf(a, w0.y, acc.y);
                acc.z = fmaf(a, w1.x, acc.z);
                acc.w = fmaf(a, w1.y, acc.w);
            }
        }
        int orow = r0 + row;
        if (orow < n) {
            float dsv = ds[orow];
            ushort4 o4;
            o4.x = f2bf(acc.x * dsv); o4.y = f2bf(acc.y * dsv);
            o4.z = f2bf(acc.z * dsv); o4.w = f2bf(acc.w * dsv);
            *(ushort4*)(hout + (size_t)orow * FOUT + cg) = o4;
        }
    }
}

// ---------------- final aggregation (F=32): 4 lanes/row, 16 rows/wave, fp32 out ----------------
__global__ __launch_bounds__(256) void agg_final(const ushort_t* __restrict__ h,
                                                 const int* __restrict__ row_ptr,
                                                 const int* __restrict__ col,
                                                 const float* __restrict__ ds,
                                                 const float* __restrict__ b,
                                                 float* __restrict__ out, int n) {
    constexpr int R = 64;
    __shared__ int rp[R + 1];
    const int tid = threadIdx.x, lane = tid & 63, wid = tid >> 6;
    const int r0 = blockIdx.x * R;
    if (tid <= R) rp[tid] = row_ptr[min(r0 + tid, n)];
    __syncthreads();
    const int sub = lane >> 2;        // 0..15
    const int fb = (lane & 3) * 8;    // feature offset
    const int row = wid * 16 + sub;
    const int g = r0 + row;
    if (g >= n) return;
    v2f acc[4];
    int4 q = *(const int4*)(h + (size_t)g * 32 + fb);
    acc[0] = unpk(q.x); acc[1] = unpk(q.y);
    acc[2] = unpk(q.z); acc[3] = unpk(q.w);
    agg_edges_v8<32>(h, col, rp[row], rp[row + 1], fb, acc);
    float dsv = ds[g];
    float4 b0 = *(const float4*)(b + fb);
    float4 b1 = *(const float4*)(b + fb + 4);
    float4 o0, o1;
    o0.x = fmaf(acc[0].x, dsv, b0.x); o0.y = fmaf(acc[0].y, dsv, b0.y);
    o0.z = fmaf(acc[1].x, dsv, b0.z); o0.w = fmaf(acc[1].y, dsv, b0.w);
    o1.x = fmaf(acc[2].x, dsv, b1.x); o1.y = fmaf(acc[2].y, dsv, b1.y);
    o1.z = fmaf(acc[3].x, dsv, b1.z); o1.w = fmaf(acc[3].y, dsv, b1.w);
    *(float4*)(out + (size_t)g * 32 + fb) = o0;
    *(float4*)(out + (size_t)g * 32 + fb + 4) = o1;
}

extern "C" void kernel_launch(void* const* d_in, const int* in_sizes, int n_in,
                              void* d_out, int out_size, void* d_ws, size_t ws_size,
                              hipStream_t stream) {
    const float* x  = (const float*)d_in[0];
    const int* edge = (const int*)d_in[1];
    const float* W1 = (const float*)d_in[2];
    const float* b1 = (const float*)d_in[3];
    const float* W2 = (const float*)d_in[4];
    const float* b2 = (const float*)d_in[5];
    const float* W3 = (const float*)d_in[6];
    const float* b3 = (const float*)d_in[7];
    const float* W4 = (const float*)d_in[8];
    const float* b4 = (const float*)d_in[9];

    const int N = NN;
    const int E = in_sizes[1] / 2;
    const int* src = edge;
    const int* dst = edge + E;

    char* ws = (char*)d_ws;
    size_t off = 0;
    auto alloc = [&](size_t bytes) -> void* {
        void* p = ws + off;
        off += (bytes + 255) & ~(size_t)255;
        return p;
    };
    int* gfill     = (int*)alloc((size_t)(NB + 1) * sizeof(int));
    int* bbase     = (int*)alloc((size_t)(NB + 1) * sizeof(int));
    int* row_ptr   = (int*)alloc((size_t)(N + 1) * sizeof(int));
    int* col       = (int*)alloc((size_t)E * sizeof(int));
    int* stage     = (int*)alloc(((size_t)NB << SCAP_SHIFT) * sizeof(int));
    float* dis     = (float*)alloc((size_t)N * sizeof(float));
    ushort_t* hbA  = (ushort_t*)alloc((size_t)N * 64 * sizeof(ushort_t));
    ushort_t* hbB  = (ushort_t*)alloc((size_t)N * 64 * sizeof(ushort_t));

    const int nea = (E + EPA - 1) / EPA;

    zero_small<<<2, 256, 0, stream>>>(gfill, NB + 1);
    stage_edges<<<nea, 256, 0, stream>>>(src, dst, gfill, stage, E);
    scan_buckets<<<1, 512, 0, stream>>>(gfill, bbase, row_ptr, N);
    build_csr<<<NB, 256, 0, stream>>>(bbase, stage, row_ptr, dis, col, N);

    // layer 1 GEMM: x (fp32) @ W1, ds-scaled -> hbA (bf16)
    gemm_lds<64, 16><<<(N + 15) / 16, 256, 0, stream>>>(x, W1, dis, N, hbA);
    // fused agg1+gemm2, agg2+gemm3, agg3+gemm4 (all ds-scaled bf16 out)
    agg_gemm<64><<<(N + 31) / 32, 256, 0, stream>>>(hbA, row_ptr, col, dis, b1, W2, N, hbB);
    agg_gemm<64><<<(N + 31) / 32, 256, 0, stream>>>(hbB, row_ptr, col, dis, b2, W3, N, hbA);
    agg_gemm<32><<<(N + 31) / 32, 256, 0, stream>>>(hbA, row_ptr, col, dis, b3, W4, N, hbB);
    // final aggregation (F=32) -> d_out fp32
    agg_final<<<(N + 63) / 64, 256, 0, stream>>>(hbB, row_ptr, col, dis, b4, (float*)d_out, N);
}

// Round 16
// 396.374 us; speedup vs baseline: 1.0050x; 1.0050x over previous
//
#include <hip/hip_runtime.h>

#define NN 100000
#define BSHIFT 8
#define NB 391        // ceil(NN / 256)
#define EPA 4096      // edges per stage block
#define SCAP_SHIFT 12 // 4096 ints per fixed bucket region (mean 2046, +45 sigma safe)

typedef unsigned short ushort_t;
typedef float v2f __attribute__((ext_vector_type(2)));

__device__ inline ushort_t f2bf(float f) {
    unsigned int b = __float_as_uint(f);
    unsigned int r = (b + 0x7FFFu + ((b >> 16) & 1u)) >> 16;
    return (ushort_t)r;
}
// unpack 2 bf16 (packed in int) -> float2; add compiles to v_pk_add_f32
__device__ inline v2f unpk(int u) {
    v2f r;
    r.x = __int_as_float(u << 16);
    r.y = __int_as_float(u & 0xffff0000);
    return r;
}

// ---------------- zero bucket fill counters ----------------
__global__ __launch_bounds__(256) void zero_small(int* __restrict__ p, int n) {
    int i = blockIdx.x * 256 + threadIdx.x;
    if (i < n) p[i] = 0;
}

// ---------------- single-pass stage into fixed-capacity bucket regions ----------------
__global__ __launch_bounds__(256) void stage_edges(const int* __restrict__ src,
                                                   const int* __restrict__ dst,
                                                   int* __restrict__ gfill,
                                                   int* __restrict__ stage, int E) {
    __shared__ int hist[NB];
    __shared__ int base[NB];
    const int tid = threadIdx.x;
    const int e0 = blockIdx.x * EPA;
    for (int i = tid; i < NB; i += 256) hist[i] = 0;
    __syncthreads();
    int es[16], eb[16];
#pragma unroll
    for (int k = 0; k < 16; ++k) {
        int e = e0 + k * 256 + tid;
        if (e < E) {
            int d = dst[e];
            eb[k] = d >> BSHIFT;
            es[k] = src[e] | ((d & 255) << 17);
            atomicAdd(&hist[eb[k]], 1);
        } else {
            eb[k] = -1;
        }
    }
    __syncthreads();
    for (int i = tid; i < NB; i += 256) {
        int c = hist[i];
        int g = (c > 0) ? atomicAdd(&gfill[i], c) : 0;
        base[i] = (i << SCAP_SHIFT) + g;
        hist[i] = 0;   // reuse as running offset
    }
    __syncthreads();
#pragma unroll
    for (int k = 0; k < 16; ++k) {
        if (eb[k] >= 0) {
            int idx = atomicAdd(&hist[eb[k]], 1);
            stage[base[eb[k]] + idx] = es[k];
        }
    }
}

// ---------------- scan 391 bucket fills -> bbase (exclusive); row_ptr[N] = E ----------------
__global__ __launch_bounds__(512) void scan_buckets(const int* __restrict__ gfill,
                                                    int* __restrict__ bbase,
                                                    int* __restrict__ row_ptr, int N) {
    __shared__ int s[512];
    const int tid = threadIdx.x;
    int v = (tid < NB) ? gfill[tid] : 0;
    s[tid] = v;
    __syncthreads();
    for (int off = 1; off < 512; off <<= 1) {
        int t = (tid >= off) ? s[tid - off] : 0;
        __syncthreads();
        if (tid >= off) s[tid] += t;
        __syncthreads();
    }
    if (tid < NB) bbase[tid] = s[tid] - v;       // exclusive
    if (tid == NB - 1) {
        bbase[NB] = s[tid];
        row_ptr[N] = s[tid];                      // = E
    }
}

// ---------------- per-bucket build: counts -> row_ptr + dinv_sqrt + place col ----------------
__global__ __launch_bounds__(256) void build_csr(const int* __restrict__ bbase,
                                                 const int* __restrict__ stage,
                                                 int* __restrict__ row_ptr,
                                                 float* __restrict__ dinv_sqrt,
                                                 int* __restrict__ col, int N) {
    __shared__ int cnt[256];
    __shared__ int rp[257];
    __shared__ int lfill[256];
    __shared__ int wsum[4];
    const int tid = threadIdx.x, lane = tid & 63, wid = tid >> 6;
    const int lo = blockIdx.x << BSHIFT;
    const int nn = min(256, N - lo);
    const int e0 = bbase[blockIdx.x];
    const int cntE = bbase[blockIdx.x + 1] - e0;
    const int* st = stage + ((size_t)blockIdx.x << SCAP_SHIFT);
    cnt[tid] = 0;
    lfill[tid] = 0;
    __syncthreads();
    for (int e = tid; e < cntE; e += 256)
        atomicAdd(&cnt[(st[e] >> 17) & 255], 1);
    __syncthreads();
    int v = cnt[tid];
    int x = v;
#pragma unroll
    for (int off = 1; off < 64; off <<= 1) {
        int y = __shfl_up(x, off, 64);
        if (lane >= off) x += y;
    }
    if (lane == 63) wsum[wid] = x;
    __syncthreads();
    int woff = 0;
    for (int w = 0; w < wid; ++w) woff += wsum[w];
    rp[tid] = e0 + woff + (x - v);
    if (tid == 255) rp[256] = e0 + woff + x;
    if (tid < nn) {
        row_ptr[lo + tid] = e0 + woff + (x - v);
        dinv_sqrt[lo + tid] = rsqrtf((float)v + 1.0f);
    }
    __syncthreads();
    for (int e = tid; e < cntE; e += 256) {
        int s = st[e];
        int dloc = (s >> 17) & 255;
        int pos = rp[dloc] + atomicAdd(&lfill[dloc], 1);
        col[pos] = s & 0x1FFFF;
    }
}

// ---------------- edge sum: 8 features/lane (int4 = 8 bf16, 16B gather), pk-f32 adds ----------------
template <int F>
__device__ inline void agg_edges_v8(const ushort_t* __restrict__ h,
                                    const int* __restrict__ col,
                                    int e0, int e1, int fb, v2f* __restrict__ acc) {
    int e = e0;
    for (; e + 8 <= e1; e += 8) {
        int c[8];
#pragma unroll
        for (int j = 0; j < 8; ++j) c[j] = col[e + j];
        int4 q[8];
#pragma unroll
        for (int j = 0; j < 8; ++j) q[j] = *(const int4*)(h + (size_t)c[j] * F + fb);
#pragma unroll
        for (int j = 0; j < 8; ++j) {
            acc[0] += unpk(q[j].x);
            acc[1] += unpk(q[j].y);
            acc[2] += unpk(q[j].z);
            acc[3] += unpk(q[j].w);
        }
    }
    if (e + 4 <= e1) {
        int c[4];
#pragma unroll
        for (int j = 0; j < 4; ++j) c[j] = col[e + j];
        int4 q[4];
#pragma unroll
        for (int j = 0; j < 4; ++j) q[j] = *(const int4*)(h + (size_t)c[j] * F + fb);
#pragma unroll
        for (int j = 0; j < 4; ++j) {
            acc[0] += unpk(q[j].x);
            acc[1] += unpk(q[j].y);
            acc[2] += unpk(q[j].z);
            acc[3] += unpk(q[j].w);
        }
        e += 4;
    }
    for (; e < e1; ++e) {
        int4 q = *(const int4*)(h + (size_t)col[e] * F + fb);
        acc[0] += unpk(q.x);
        acc[1] += unpk(q.y);
        acc[2] += unpk(q.z);
        acc[3] += unpk(q.w);
    }
}

// ---------------- dense GEMM h' = ds[row] * (in @ W), LDS-tiled, bf16 output ----------------
// phase B register-blocked: 2 rows per thread share each W load (halves W-LDS traffic).
template <int FOUT, int R>
__global__ __launch_bounds__(256) void gemm_lds(const float* __restrict__ in,
                                                const float* __restrict__ W,
                                                const float* __restrict__ ds, int n,
                                                ushort_t* __restrict__ h) {
    constexpr int XS = 68;
    __shared__ float xs[R * XS];
    __shared__ float ws[64 * FOUT];
    const int tid = threadIdx.x;
    const int r0 = blockIdx.x * R;
    {
        const float4* xsrc = (const float4*)(in + (size_t)r0 * 64);
        constexpr int NF4 = R * 16;
#pragma unroll
        for (int i = tid; i < NF4; i += 256) {
            int row = i >> 4, kk = (i & 15) << 2;
            float4 v = make_float4(0.f, 0.f, 0.f, 0.f);
            if (r0 + row < n) v = xsrc[i];
            *(float4*)(xs + row * XS + kk) = v;
        }
        const float4* wsrc = (const float4*)W;
#pragma unroll
        for (int i = tid; i < 64 * FOUT / 4; i += 256)
            *(float4*)(ws + i * 4) = wsrc[i];
    }
    __syncthreads();
    constexpr int CG = FOUT / 4;
    constexpr int HALF = (R * CG) / 2;
    if (tid < HALF) {
        const int row0 = tid / CG;             // 0 .. R/2-1
        const int row1 = row0 + R / 2;
        const int col = (tid % CG) * 4;
        float4 a0 = make_float4(0.f, 0.f, 0.f, 0.f);
        float4 a1 = make_float4(0.f, 0.f, 0.f, 0.f);
#pragma unroll
        for (int k = 0; k < 64; k += 4) {
            float4 x0 = *(const float4*)(xs + row0 * XS + k);
            float4 x1 = *(const float4*)(xs + row1 * XS + k);
#pragma unroll
            for (int kk = 0; kk < 4; ++kk) {
                float4 wv = *(const float4*)(ws + (k + kk) * FOUT + col);
                float b0 = (&x0.x)[kk], b1 = (&x1.x)[kk];
                a0.x = fmaf(b0, wv.x, a0.x); a0.y = fmaf(b0, wv.y, a0.y);
                a0.z = fmaf(b0, wv.z, a0.z); a0.w = fmaf(b0, wv.w, a0.w);
                a1.x = fmaf(b1, wv.x, a1.x); a1.y = fmaf(b1, wv.y, a1.y);
                a1.z = fmaf(b1, wv.z, a1.z); a1.w = fmaf(b1, wv.w, a1.w);
            }
        }
        int o0 = r0 + row0, o1 = r0 + row1;
        if (o0 < n) {
            float dsv = ds[o0];
            ushort4 o;
            o.x = f2bf(a0.x * dsv); o.y = f2bf(a0.y * dsv);
            o.z = f2bf(a0.z * dsv); o.w = f2bf(a0.w * dsv);
            *(ushort4*)(h + (size_t)o0 * FOUT + col) = o;
        }
        if (o1 < n) {
            float dsv = ds[o1];
            ushort4 o;
            o.x = f2bf(a1.x * dsv); o.y = f2bf(a1.y * dsv);
            o.z = f2bf(a1.z * dsv); o.w = f2bf(a1.w * dsv);
            *(ushort4*)(h + (size_t)o1 * FOUT + col) = o;
        }
    }
}

// ---------------- FUSED agg+gemm: 8 lanes/row (16B gathers), 8 rows/wave, R=32 ----------------
// phase B register-blocked: 2 rows per thread share each W load.
template <int FOUT>
__global__ __launch_bounds__(256) void agg_gemm(const ushort_t* __restrict__ hin,
                                                const int* __restrict__ row_ptr,
                                                const int* __restrict__ col,
                                                const float* __restrict__ ds,
                                                const float* __restrict__ bagg,
                                                const float* __restrict__ W, int n,
                                                ushort_t* __restrict__ hout) {
    constexpr int R = 32;
    constexpr int XS = 68;
    __shared__ float xs[R * XS];
    __shared__ float ws[64 * FOUT];
    __shared__ int rp[R + 1];
    const int tid = threadIdx.x, lane = tid & 63, wid = tid >> 6;
    const int r0 = blockIdx.x * R;
    // stage W (fp32)
    const float4* wsrc = (const float4*)W;
#pragma unroll
    for (int i = tid; i < 64 * FOUT / 4; i += 256)
        *(float4*)(ws + i * 4) = wsrc[i];
    if (tid <= R) rp[tid] = row_ptr[min(r0 + tid, n)];
    __syncthreads();
    // phase A: 8 rows per wave, 8 lanes per row, 8 features/lane
    {
        const int sub = lane >> 3;        // 0..7
        const int fb = (lane & 7) * 8;    // feature offset
        const int row = wid * 8 + sub;
        const int g = r0 + row;
        v2f acc[4];
        acc[0] = 0.f; acc[1] = 0.f; acc[2] = 0.f; acc[3] = 0.f;
        if (g < n) {
            int4 q = *(const int4*)(hin + (size_t)g * 64 + fb);
            acc[0] = unpk(q.x); acc[1] = unpk(q.y);
            acc[2] = unpk(q.z); acc[3] = unpk(q.w);
            agg_edges_v8<64>(hin, col, rp[row], rp[row + 1], fb, acc);
            float dsv = ds[g];
            float4 b0 = *(const float4*)(bagg + fb);
            float4 b1 = *(const float4*)(bagg + fb + 4);
            acc[0].x = fmaxf(fmaf(acc[0].x, dsv, b0.x), 0.f);
            acc[0].y = fmaxf(fmaf(acc[0].y, dsv, b0.y), 0.f);
            acc[1].x = fmaxf(fmaf(acc[1].x, dsv, b0.z), 0.f);
            acc[1].y = fmaxf(fmaf(acc[1].y, dsv, b0.w), 0.f);
            acc[2].x = fmaxf(fmaf(acc[2].x, dsv, b1.x), 0.f);
            acc[2].y = fmaxf(fmaf(acc[2].y, dsv, b1.y), 0.f);
            acc[3].x = fmaxf(fmaf(acc[3].x, dsv, b1.z), 0.f);
            acc[3].y = fmaxf(fmaf(acc[3].y, dsv, b1.w), 0.f);
        }
        float4 o0 = make_float4(acc[0].x, acc[0].y, acc[1].x, acc[1].y);
        float4 o1 = make_float4(acc[2].x, acc[2].y, acc[3].x, acc[3].y);
        *(float4*)(xs + row * XS + fb) = o0;
        *(float4*)(xs + row * XS + fb + 4) = o1;
    }
    __syncthreads();
    // phase B: GEMM from xs, 2 rows/thread, hout = ds * (xs @ W), bf16
    constexpr int CG = FOUT / 4;
    constexpr int HALF = (R * CG) / 2;
    if (tid < HALF) {
        const int row0 = tid / CG;          // 0..15
        const int row1 = row0 + R / 2;      // +16
        const int cg = (tid % CG) * 4;
        float4 a0 = make_float4(0.f, 0.f, 0.f, 0.f);
        float4 a1 = make_float4(0.f, 0.f, 0.f, 0.f);
#pragma unroll
        for (int k = 0; k < 64; k += 4) {
            float4 x0 = *(const float4*)(xs + row0 * XS + k);
            float4 x1 = *(const float4*)(xs + row1 * XS + k);
#pragma unroll
            for (int kk = 0; kk < 4; ++kk) {
                float4 wv = *(const float4*)(ws + (k + kk) * FOUT + cg);
                float b0 = (&x0.x)[kk], b1 = (&x1.x)[kk];
                a0.x = fmaf(b0, wv.x, a0.x); a0.y = fmaf(b0, wv.y, a0.y);
                a0.z = fmaf(b0, wv.z, a0.z); a0.w = fmaf(b0, wv.w, a0.w);
                a1.x = fmaf(b1, wv.x, a1.x); a1.y = fmaf(b1, wv.y, a1.y);
                a1.z = fmaf(b1, wv.z, a1.z); a1.w = fmaf(b1, wv.w, a1.w);
            }
        }
        int g0 = r0 + row0, g1 = r0 + row1;
        if (g0 < n) {
            float dsv = ds[g0];
            ushort4 o4;
            o4.x = f2bf(a0.x * dsv); o4.y = f2bf(a0.y * dsv);
            o4.z = f2bf(a0.z * dsv); o4.w = f2bf(a0.w * dsv);
            *(ushort4*)(hout + (size_t)g0 * FOUT + cg) = o4;
        }
        if (g1 < n) {
            float dsv = ds[g1];
            ushort4 o4;
            o4.x = f2bf(a1.x * dsv); o4.y = f2bf(a1.y * dsv);
            o4.z = f2bf(a1.z * dsv); o4.w = f2bf(a1.w * dsv);
            *(ushort4*)(hout + (size_t)g1 * FOUT + cg) = o4;
        }
    }
}

// ---------------- final aggregation (F=32): 4 lanes/row, 16 rows/wave, fp32 out ----------------
__global__ __launch_bounds__(256) void agg_final(const ushort_t* __restrict__ h,
                                                 const int* __restrict__ row_ptr,
                                                 const int* __restrict__ col,
                                                 const float* __restrict__ ds,
                                                 const float* __restrict__ b,
                                                 float* __restrict__ out, int n) {
    constexpr int R = 64;
    __shared__ int rp[R + 1];
    const int tid = threadIdx.x, lane = tid & 63, wid = tid >> 6;
    const int r0 = blockIdx.x * R;
    if (tid <= R) rp[tid] = row_ptr[min(r0 + tid, n)];
    __syncthreads();
    const int sub = lane >> 2;        // 0..15
    const int fb = (lane & 3) * 8;    // feature offset
    const int row = wid * 16 + sub;
    const int g = r0 + row;
    if (g >= n) return;
    v2f acc[4];
    int4 q = *(const int4*)(h + (size_t)g * 32 + fb);
    acc[0] = unpk(q.x); acc[1] = unpk(q.y);
    acc[2] = unpk(q.z); acc[3] = unpk(q.w);
    agg_edges_v8<32>(h, col, rp[row], rp[row + 1], fb, acc);
    float dsv = ds[g];
    float4 b0 = *(const float4*)(b + fb);
    float4 b1 = *(const float4*)(b + fb + 4);
    float4 o0, o1;
    o0.x = fmaf(acc[0].x, dsv, b0.x); o0.y = fmaf(acc[0].y, dsv, b0.y);
    o0.z = fmaf(acc[1].x, dsv, b0.z); o0.w = fmaf(acc[1].y, dsv, b0.w);
    o1.x = fmaf(acc[2].x, dsv, b1.x); o1.y = fmaf(acc[2].y, dsv, b1.y);
    o1.z = fmaf(acc[3].x, dsv, b1.z); o1.w = fmaf(acc[3].y, dsv, b1.w);
    *(float4*)(out + (size_t)g * 32 + fb) = o0;
    *(float4*)(out + (size_t)g * 32 + fb + 4) = o1;
}

extern "C" void kernel_launch(void* const* d_in, const int* in_sizes, int n_in,
                              void* d_out, int out_size, void* d_ws, size_t ws_size,
                              hipStream_t stream) {
    const float* x  = (const float*)d_in[0];
    const int* edge = (const int*)d_in[1];
    const float* W1 = (const float*)d_in[2];
    const float* b1 = (const float*)d_in[3];
    const float* W2 = (const float*)d_in[4];
    const float* b2 = (const float*)d_in[5];
    const float* W3 = (const float*)d_in[6];
    const float* b3 = (const float*)d_in[7];
    const float* W4 = (const float*)d_in[8];
    const float* b4 = (const float*)d_in[9];

    const int N = NN;
    const int E = in_sizes[1] / 2;
    const int* src = edge;
    const int* dst = edge + E;

    char* ws = (char*)d_ws;
    size_t off = 0;
    auto alloc = [&](size_t bytes) -> void* {
        void* p = ws + off;
        off += (bytes + 255) & ~(size_t)255;
        return p;
    };
    int* gfill     = (int*)alloc((size_t)(NB + 1) * sizeof(int));
    int* bbase     = (int*)alloc((size_t)(NB + 1) * sizeof(int));
    int* row_ptr   = (int*)alloc((size_t)(N + 1) * sizeof(int));
    int* col       = (int*)alloc((size_t)E * sizeof(int));
    int* stage     = (int*)alloc(((size_t)NB << SCAP_SHIFT) * sizeof(int));
    float* dis     = (float*)alloc((size_t)N * sizeof(float));
    ushort_t* hbA  = (ushort_t*)alloc((size_t)N * 64 * sizeof(ushort_t));
    ushort_t* hbB  = (ushort_t*)alloc((size_t)N * 64 * sizeof(ushort_t));

    const int nea = (E + EPA - 1) / EPA;

    zero_small<<<2, 256, 0, stream>>>(gfill, NB + 1);
    stage_edges<<<nea, 256, 0, stream>>>(src, dst, gfill, stage, E);
    scan_buckets<<<1, 512, 0, stream>>>(gfill, bbase, row_ptr, N);
    build_csr<<<NB, 256, 0, stream>>>(bbase, stage, row_ptr, dis, col, N);

    // layer 1 GEMM: x (fp32) @ W1, ds-scaled -> hbA (bf16)
    gemm_lds<64, 16><<<(N + 15) / 16, 256, 0, stream>>>(x, W1, dis, N, hbA);
    // fused agg1+gemm2, agg2+gemm3, agg3+gemm4 (all ds-scaled bf16 out)
    agg_gemm<64><<<(N + 31) / 32, 256, 0, stream>>>(hbA, row_ptr, col, dis, b1, W2, N, hbB);
    agg_gemm<64><<<(N + 31) / 32, 256, 0, stream>>>(hbB, row_ptr, col, dis, b2, W3, N, hbA);
    agg_gemm<32><<<(N + 31) / 32, 256, 0, stream>>>(hbA, row_ptr, col, dis, b3, W4, N, hbB);
    // final aggregation (F=32) -> d_out fp32
    agg_final<<<(N + 63) / 64, 256, 0, stream>>>(hbB, row_ptr, col, dis, b4, (float*)d_out, N);
}

// Round 17
// 166.277 us; speedup vs baseline: 2.3956x; 2.3838x over previous
//
#include <hip/hip_runtime.h>

#define NN 100000
#define BSHIFT 8
#define NB 391        // ceil(NN / 256)
#define EPA 4096      // edges per stage block
#define SCAP_SHIFT 12 // 4096 ints per fixed bucket region (mean 2046, +45 sigma safe)

typedef unsigned short ushort_t;
typedef float v2f __attribute__((ext_vector_type(2)));

__device__ inline ushort_t f2bf(float f) {
    unsigned int b = __float_as_uint(f);
    unsigned int r = (b + 0x7FFFu + ((b >> 16) & 1u)) >> 16;
    return (ushort_t)r;
}
// unpack 2 bf16 (packed in int) -> float2; add compiles to v_pk_add_f32
__device__ inline v2f unpk(int u) {
    v2f r;
    r.x = __int_as_float(u << 16);
    r.y = __int_as_float(u & 0xffff0000);
    return r;
}

// ---------------- zero bucket fill counters ----------------
__global__ __launch_bounds__(256) void zero_small(int* __restrict__ p, int n) {
    int i = blockIdx.x * 256 + threadIdx.x;
    if (i < n) p[i] = 0;
}

// ---------------- single-pass stage into fixed-capacity bucket regions ----------------
__global__ __launch_bounds__(256) void stage_edges(const int* __restrict__ src,
                                                   const int* __restrict__ dst,
                                                   int* __restrict__ gfill,
                                                   int* __restrict__ stage, int E) {
    __shared__ int hist[NB];
    __shared__ int base[NB];
    const int tid = threadIdx.x;
    const int e0 = blockIdx.x * EPA;
    for (int i = tid; i < NB; i += 256) hist[i] = 0;
    __syncthreads();
    int es[16], eb[16];
#pragma unroll
    for (int k = 0; k < 16; ++k) {
        int e = e0 + k * 256 + tid;
        if (e < E) {
            int d = dst[e];
            eb[k] = d >> BSHIFT;
            es[k] = src[e] | ((d & 255) << 17);
            atomicAdd(&hist[eb[k]], 1);
        } else {
            eb[k] = -1;
        }
    }
    __syncthreads();
    for (int i = tid; i < NB; i += 256) {
        int c = hist[i];
        int g = (c > 0) ? atomicAdd(&gfill[i], c) : 0;
        base[i] = (i << SCAP_SHIFT) + g;
        hist[i] = 0;   // reuse as running offset
    }
    __syncthreads();
#pragma unroll
    for (int k = 0; k < 16; ++k) {
        if (eb[k] >= 0) {
            int idx = atomicAdd(&hist[eb[k]], 1);
            stage[base[eb[k]] + idx] = es[k];
        }
    }
}

// ---------------- scan 391 bucket fills -> bbase (exclusive); row_ptr[N] = E ----------------
__global__ __launch_bounds__(512) void scan_buckets(const int* __restrict__ gfill,
                                                    int* __restrict__ bbase,
                                                    int* __restrict__ row_ptr, int N) {
    __shared__ int s[512];
    const int tid = threadIdx.x;
    int v = (tid < NB) ? gfill[tid] : 0;
    s[tid] = v;
    __syncthreads();
    for (int off = 1; off < 512; off <<= 1) {
        int t = (tid >= off) ? s[tid - off] : 0;
        __syncthreads();
        if (tid >= off) s[tid] += t;
        __syncthreads();
    }
    if (tid < NB) bbase[tid] = s[tid] - v;       // exclusive
    if (tid == NB - 1) {
        bbase[NB] = s[tid];
        row_ptr[N] = s[tid];                      // = E
    }
}

// ---------------- per-bucket build: counts -> row_ptr + dinv_sqrt + place col ----------------
__global__ __launch_bounds__(256) void build_csr(const int* __restrict__ bbase,
                                                 const int* __restrict__ stage,
                                                 int* __restrict__ row_ptr,
                                                 float* __restrict__ dinv_sqrt,
                                                 int* __restrict__ col, int N) {
    __shared__ int cnt[256];
    __shared__ int rp[257];
    __shared__ int lfill[256];
    __shared__ int wsum[4];
    const int tid = threadIdx.x, lane = tid & 63, wid = tid >> 6;
    const int lo = blockIdx.x << BSHIFT;
    const int nn = min(256, N - lo);
    const int e0 = bbase[blockIdx.x];
    const int cntE = bbase[blockIdx.x + 1] - e0;
    const int* st = stage + ((size_t)blockIdx.x << SCAP_SHIFT);
    cnt[tid] = 0;
    lfill[tid] = 0;
    __syncthreads();
    for (int e = tid; e < cntE; e += 256)
        atomicAdd(&cnt[(st[e] >> 17) & 255], 1);
    __syncthreads();
    int v = cnt[tid];
    int x = v;
#pragma unroll
    for (int off = 1; off < 64; off <<= 1) {
        int y = __shfl_up(x, off, 64);
        if (lane >= off) x += y;
    }
    if (lane == 63) wsum[wid] = x;
    __syncthreads();
    int woff = 0;
    for (int w = 0; w < wid; ++w) woff += wsum[w];
    rp[tid] = e0 + woff + (x - v);
    if (tid == 255) rp[256] = e0 + woff + x;
    if (tid < nn) {
        row_ptr[lo + tid] = e0 + woff + (x - v);
        dinv_sqrt[lo + tid] = rsqrtf((float)v + 1.0f);
    }
    __syncthreads();
    for (int e = tid; e < cntE; e += 256) {
        int s = st[e];
        int dloc = (s >> 17) & 255;
        int pos = rp[dloc] + atomicAdd(&lfill[dloc], 1);
        col[pos] = s & 0x1FFFF;
    }
}

// ---------------- edge sum: 8 features/lane (int4 = 8 bf16, 16B gather), pk-f32 adds ----------------
template <int F>
__device__ inline void agg_edges_v8(const ushort_t* __restrict__ h,
                                    const int* __restrict__ col,
                                    int e0, int e1, int fb, v2f* __restrict__ acc) {
    int e = e0;
    for (; e + 8 <= e1; e += 8) {
        int c[8];
#pragma unroll
        for (int j = 0; j < 8; ++j) c[j] = col[e + j];
        int4 q[8];
#pragma unroll
        for (int j = 0; j < 8; ++j) q[j] = *(const int4*)(h + (size_t)c[j] * F + fb);
#pragma unroll
        for (int j = 0; j < 8; ++j) {
            acc[0] += unpk(q[j].x);
            acc[1] += unpk(q[j].y);
            acc[2] += unpk(q[j].z);
            acc[3] += unpk(q[j].w);
        }
    }
    if (e + 4 <= e1) {
        int c[4];
#pragma unroll
        for (int j = 0; j < 4; ++j) c[j] = col[e + j];
        int4 q[4];
#pragma unroll
        for (int j = 0; j < 4; ++j) q[j] = *(const int4*)(h + (size_t)c[j] * F + fb);
#pragma unroll
        for (int j = 0; j < 4; ++j) {
            acc[0] += unpk(q[j].x);
            acc[1] += unpk(q[j].y);
            acc[2] += unpk(q[j].z);
            acc[3] += unpk(q[j].w);
        }
        e += 4;
    }
    for (; e < e1; ++e) {
        int4 q = *(const int4*)(h + (size_t)col[e] * F + fb);
        acc[0] += unpk(q.x);
        acc[1] += unpk(q.y);
        acc[2] += unpk(q.z);
        acc[3] += unpk(q.w);
    }
}

// ---------------- dense GEMM h' = ds[row] * (in @ W), LDS-tiled, bf16 output ----------------
template <int FOUT, int R>
__global__ __launch_bounds__(256) void gemm_lds(const float* __restrict__ in,
                                                const float* __restrict__ W,
                                                const float* __restrict__ ds, int n,
                                                ushort_t* __restrict__ h) {
    constexpr int XS = 68;
    __shared__ float xs[R * XS];
    __shared__ float ws[64 * FOUT];
    const int tid = threadIdx.x;
    const int r0 = blockIdx.x * R;
    {
        const float4* xsrc = (const float4*)(in + (size_t)r0 * 64);
        constexpr int NF4 = R * 16;
#pragma unroll
        for (int i = tid; i < NF4; i += 256) {
            int row = i >> 4, kk = (i & 15) << 2;
            float4 v = make_float4(0.f, 0.f, 0.f, 0.f);
            if (r0 + row < n) v = xsrc[i];
            *(float4*)(xs + row * XS + kk) = v;
        }
        const float4* wsrc = (const float4*)W;
#pragma unroll
        for (int i = tid; i < 64 * FOUT / 4; i += 256)
            *(float4*)(ws + i * 4) = wsrc[i];
    }
    __syncthreads();
    constexpr int CG = FOUT / 4;
    const int row = tid / CG;
    const int col = (tid % CG) * 4;
    float4 acc = make_float4(0.f, 0.f, 0.f, 0.f);
#pragma unroll
    for (int k = 0; k < 64; k += 4) {
        float4 xv = *(const float4*)(xs + row * XS + k);
#pragma unroll
        for (int kk = 0; kk < 4; ++kk) {
            float a = (&xv.x)[kk];
            float4 wv = *(const float4*)(ws + (k + kk) * FOUT + col);
            acc.x = fmaf(a, wv.x, acc.x);
            acc.y = fmaf(a, wv.y, acc.y);
            acc.z = fmaf(a, wv.z, acc.z);
            acc.w = fmaf(a, wv.w, acc.w);
        }
    }
    int orow = r0 + row;
    if (orow < n) {
        float dsv = ds[orow];
        ushort4 o;
        o.x = f2bf(acc.x * dsv); o.y = f2bf(acc.y * dsv);
        o.z = f2bf(acc.z * dsv); o.w = f2bf(acc.w * dsv);
        *(ushort4*)(h + (size_t)orow * FOUT + col) = o;
    }
}

// ---------------- FUSED agg+gemm: 8 lanes/row (16B gathers), 8 rows/wave, R=32 ----------------
template <int FOUT>
__global__ __launch_bounds__(256) void agg_gemm(const ushort_t* __restrict__ hin,
                                                const int* __restrict__ row_ptr,
                                                const int* __restrict__ col,
                                                const float* __restrict__ ds,
                                                const float* __restrict__ bagg,
                                                const float* __restrict__ W, int n,
                                                ushort_t* __restrict__ hout) {
    constexpr int R = 32;
    constexpr int XS = 68;
    __shared__ float xs[R * XS];
    __shared__ float ws[64 * FOUT];
    __shared__ int rp[R + 1];
    const int tid = threadIdx.x, lane = tid & 63, wid = tid >> 6;
    const int r0 = blockIdx.x * R;
    // stage W (fp32)
    const float4* wsrc = (const float4*)W;
#pragma unroll
    for (int i = tid; i < 64 * FOUT / 4; i += 256)
        *(float4*)(ws + i * 4) = wsrc[i];
    if (tid <= R) rp[tid] = row_ptr[min(r0 + tid, n)];
    __syncthreads();
    // phase A: 8 rows per wave, 8 lanes per row, 8 features/lane
    {
        const int sub = lane >> 3;        // 0..7
        const int fb = (lane & 7) * 8;    // feature offset
        const int row = wid * 8 + sub;
        const int g = r0 + row;
        v2f acc[4];
        acc[0] = 0.f; acc[1] = 0.f; acc[2] = 0.f; acc[3] = 0.f;
        if (g < n) {
            int4 q = *(const int4*)(hin + (size_t)g * 64 + fb);
            acc[0] = unpk(q.x); acc[1] = unpk(q.y);
            acc[2] = unpk(q.z); acc[3] = unpk(q.w);
            agg_edges_v8<64>(hin, col, rp[row], rp[row + 1], fb, acc);
            float dsv = ds[g];
            float4 b0 = *(const float4*)(bagg + fb);
            float4 b1 = *(const float4*)(bagg + fb + 4);
            acc[0].x = fmaxf(fmaf(acc[0].x, dsv, b0.x), 0.f);
            acc[0].y = fmaxf(fmaf(acc[0].y, dsv, b0.y), 0.f);
            acc[1].x = fmaxf(fmaf(acc[1].x, dsv, b0.z), 0.f);
            acc[1].y = fmaxf(fmaf(acc[1].y, dsv, b0.w), 0.f);
            acc[2].x = fmaxf(fmaf(acc[2].x, dsv, b1.x), 0.f);
            acc[2].y = fmaxf(fmaf(acc[2].y, dsv, b1.y), 0.f);
            acc[3].x = fmaxf(fmaf(acc[3].x, dsv, b1.z), 0.f);
            acc[3].y = fmaxf(fmaf(acc[3].y, dsv, b1.w), 0.f);
        }
        float4 o0 = make_float4(acc[0].x, acc[0].y, acc[1].x, acc[1].y);
        float4 o1 = make_float4(acc[2].x, acc[2].y, acc[3].x, acc[3].y);
        *(float4*)(xs + row * XS + fb) = o0;
        *(float4*)(xs + row * XS + fb + 4) = o1;
    }
    __syncthreads();
    // phase B: GEMM from xs, hout = ds * (xs @ W), bf16
    constexpr int CG = FOUT / 4;
    for (int o = tid; o < R * CG; o += 256) {
        int row = o / CG;
        int cg = (o % CG) * 4;
        float4 acc = make_float4(0.f, 0.f, 0.f, 0.f);
#pragma unroll
        for (int k = 0; k < 64; k += 4) {
            float4 xv = *(const float4*)(xs + row * XS + k);
#pragma unroll
            for (int kk = 0; kk < 4; ++kk) {
                float a = (&xv.x)[kk];
                float4 wv = *(const float4*)(ws + (k + kk) * FOUT + cg);
                acc.x = fmaf(a, wv.x, acc.x);
                acc.y = fmaf(a, wv.y, acc.y);
                acc.z = fmaf(a, wv.z, acc.z);
                acc.w = fmaf(a, wv.w, acc.w);
            }
        }
        int orow = r0 + row;
        if (orow < n) {
            float dsv = ds[orow];
            ushort4 o4;
            o4.x = f2bf(acc.x * dsv); o4.y = f2bf(acc.y * dsv);
            o4.z = f2bf(acc.z * dsv); o4.w = f2bf(acc.w * dsv);
            *(ushort4*)(hout + (size_t)orow * FOUT + cg) = o4;
        }
    }
}

// ---------------- final aggregation (F=32): 4 lanes/row, 16 rows/wave, fp32 out ----------------
__global__ __launch_bounds__(256) void agg_final(const ushort_t* __restrict__ h,
                                                 const int* __restrict__ row_ptr,
                                                 const int* __restrict__ col,
                                                 const float* __restrict__ ds,
                                                 const float* __restrict__ b,
                                                 float* __restrict__ out, int n) {
    constexpr int R = 64;
    __shared__ int rp[R + 1];
    const int tid = threadIdx.x, lane = tid & 63, wid = tid >> 6;
    const int r0 = blockIdx.x * R;
    if (tid <= R) rp[tid] = row_ptr[min(r0 + tid, n)];
    __syncthreads();
    const int sub = lane >> 2;        // 0..15
    const int fb = (lane & 3) * 8;    // feature offset
    const int row = wid * 16 + sub;
    const int g = r0 + row;
    if (g >= n) return;
    v2f acc[4];
    int4 q = *(const int4*)(h + (size_t)g * 32 + fb);
    acc[0] = unpk(q.x); acc[1] = unpk(q.y);
    acc[2] = unpk(q.z); acc[3] = unpk(q.w);
    agg_edges_v8<32>(h, col, rp[row], rp[row + 1], fb, acc);
    float dsv = ds[g];
    float4 b0 = *(const float4*)(b + fb);
    float4 b1 = *(const float4*)(b + fb + 4);
    float4 o0, o1;
    o0.x = fmaf(acc[0].x, dsv, b0.x); o0.y = fmaf(acc[0].y, dsv, b0.y);
    o0.z = fmaf(acc[1].x, dsv, b0.z); o0.w = fmaf(acc[1].y, dsv, b0.w);
    o1.x = fmaf(acc[2].x, dsv, b1.x); o1.y = fmaf(acc[2].y, dsv, b1.y);
    o1.z = fmaf(acc[3].x, dsv, b1.z); o1.w = fmaf(acc[3].y, dsv, b1.w);
    *(float4*)(out + (size_t)g * 32 + fb) = o0;
    *(float4*)(out + (size_t)g * 32 + fb + 4) = o1;
}

extern "C" void kernel_launch(void* const* d_in, const int* in_sizes, int n_in,
                              void* d_out, int out_size, void* d_ws, size_t ws_size,
                              hipStream_t stream) {
    const float* x  = (const float*)d_in[0];
    const int* edge = (const int*)d_in[1];
    const float* W1 = (const float*)d_in[2];
    const float* b1 = (const float*)d_in[3];
    const float* W2 = (const float*)d_in[4];
    const float* b2 = (const float*)d_in[5];
    const float* W3 = (const float*)d_in[6];
    const float* b3 = (const float*)d_in[7];
    const float* W4 = (const float*)d_in[8];
    const float* b4 = (const float*)d_in[9];

    const int N = NN;
    const int E = in_sizes[1] / 2;
    const int* src = edge;
    const int* dst = edge + E;

    char* ws = (char*)d_ws;
    size_t off = 0;
    auto alloc = [&](size_t bytes) -> void* {
        void* p = ws + off;
        off += (bytes + 255) & ~(size_t)255;
        return p;
    };
    int* gfill     = (int*)alloc((size_t)(NB + 1) * sizeof(int));
    int* bbase     = (int*)alloc((size_t)(NB + 1) * sizeof(int));
    int* row_ptr   = (int*)alloc((size_t)(N + 1) * sizeof(int));
    int* col       = (int*)alloc((size_t)E * sizeof(int));
    int* stage     = (int*)alloc(((size_t)NB << SCAP_SHIFT) * sizeof(int));
    float* dis     = (float*)alloc((size_t)N * sizeof(float));
    ushort_t* hbA  = (ushort_t*)alloc((size_t)N * 64 * sizeof(ushort_t));
    ushort_t* hbB  = (ushort_t*)alloc((size_t)N * 64 * sizeof(ushort_t));

    const int nea = (E + EPA - 1) / EPA;

    zero_small<<<2, 256, 0, stream>>>(gfill, NB + 1);
    stage_edges<<<nea, 256, 0, stream>>>(src, dst, gfill, stage, E);
    scan_buckets<<<1, 512, 0, stream>>>(gfill, bbase, row_ptr, N);
    build_csr<<<NB, 256, 0, stream>>>(bbase, stage, row_ptr, dis, col, N);

    // layer 1 GEMM: x (fp32) @ W1, ds-scaled -> hbA (bf16)
    gemm_lds<64, 16><<<(N + 15) / 16, 256, 0, stream>>>(x, W1, dis, N, hbA);
    // fused agg1+gemm2, agg2+gemm3, agg3+gemm4 (all ds-scaled bf16 out)
    agg_gemm<64><<<(N + 31) / 32, 256, 0, stream>>>(hbA, row_ptr, col, dis, b1, W2, N, hbB);
    agg_gemm<64><<<(N + 31) / 32, 256, 0, stream>>>(hbB, row_ptr, col, dis, b2, W3, N, hbA);
    agg_gemm<32><<<(N + 31) / 32, 256, 0, stream>>>(hbA, row_ptr, col, dis, b3, W4, N, hbB);
    // final aggregation (F=32) -> d_out fp32
    agg_final<<<(N + 63) / 64, 256, 0, stream>>>(hbB, row_ptr, col, dis, b4, (float*)d_out, N);
}